// Round 6
// baseline (419.482 us; speedup 1.0000x reference)
//
#include <hip/hip_runtime.h>

// Problem constants
#define H_DIM 2048
#define E_DIM 8
#define T_DIM 2048
#define F_DIM 4096                 // INTER*2
#define NBLK  1024                 // 8 e * 128 h-chunks; exactly 4 blocks/CU, uniform
#define HCHUNK 16                  // h-columns per block

typedef float f32x4 __attribute__((ext_vector_type(4)));

// result = sum_{e,h} A[e,h]*B[e,h];  A = sum_t mask[e,t]*hidden[t,h];  B = sum_f W[e,h,f]
// R6: PER-WAVE A, STAGGERED. A block's 16-h window is ONE 64B cacheline per
// token, so all 4 waves share the same hidden lines; each wave computes A only
// for the 4 h it streams (32 iters, in-register, no LDS/barrier/divergence).
// The A-burst is inserted after `wave` W-iterations (stagger 0/1/2/3): wave-0
// warms L2 at t=0 while 12/16 waves stream; waves 1-3 hit warm lines. Every
// wave lags ~0.7us equally (vs R5: one producer lagging ~2us). A-reduce merges
// into the epilogue shuffle pass.
__global__ __launch_bounds__(256, 4) void moe_dot(
    const float* __restrict__ hidden,   // [T, H]
    const float* __restrict__ W,        // [E, H, F]
    const float* __restrict__ mask,     // [E, T]
    float* __restrict__ out) {
  const int tid  = threadIdx.x;
  const int bid  = blockIdx.x;
  const int e    = bid >> 7;                // 0..7
  const int h0   = (bid & 127) * HCHUNK;    // 0..2032
  const int wave = tid >> 6;
  const int lane = tid & 63;

  __shared__ float wsum[4];

  // this wave's 4 h-columns / W-rows: h0 + 4*wave + j, j=0..3
  const int r0 = wave << 2;
  const f32x4* rp = (const f32x4*)(W + ((size_t)e * H_DIM + h0 + r0) * F_DIM);
  const float* hp = hidden + h0 + r0;            // f32x4 column slice
  const float* mp = mask + (size_t)e * T_DIM + lane;

  f32x4 a0 = (f32x4)0.f, a1 = (f32x4)0.f, a2 = (f32x4)0.f, a3 = (f32x4)0.f;
  f32x4 accA = (f32x4)0.f;

  // ---- stream prefix: `wave` iterations (stagger) ----
  int i = 0;
  #pragma unroll 1
  for (; i < wave; ++i) {
    int idx = lane + (i << 6);
    a0 += rp[idx];
    a1 += rp[idx + 1024];
    a2 += rp[idx + 2048];
    a3 += rp[idx + 3072];
  }

  // ---- A-burst: accA[j] = sum_t mask[e,t]*hidden[t, h0+r0+j] ----
  #pragma unroll 4
  for (int k = 0; k < 32; ++k) {
    int t = lane + (k << 6);
    accA += *(const f32x4*)(hp + (size_t)t * H_DIM) * mp[(size_t)(k << 6)];
  }

  // ---- stream rest ----
  #pragma unroll 2
  for (; i < 16; ++i) {
    int idx = lane + (i << 6);
    a0 += rp[idx];
    a1 += rp[idx + 1024];
    a2 += rp[idx + 2048];
    a3 += rp[idx + 3072];
  }

  // ---- epilogue: 8 ILP'd shuffle chains (4 row-sums + 4 A-components) ----
  float s0 = (a0.x + a0.y) + (a0.z + a0.w);
  float s1 = (a1.x + a1.y) + (a1.z + a1.w);
  float s2 = (a2.x + a2.y) + (a2.z + a2.w);
  float s3 = (a3.x + a3.y) + (a3.z + a3.w);
  #pragma unroll
  for (int off = 32; off > 0; off >>= 1) {
    s0 += __shfl_down(s0, off, 64);
    s1 += __shfl_down(s1, off, 64);
    s2 += __shfl_down(s2, off, 64);
    s3 += __shfl_down(s3, off, 64);
    accA.x += __shfl_down(accA.x, off, 64);
    accA.y += __shfl_down(accA.y, off, 64);
    accA.z += __shfl_down(accA.z, off, 64);
    accA.w += __shfl_down(accA.w, off, 64);
  }
  if (lane == 0)
    wsum[wave] = s0 * accA.x + s1 * accA.y + s2 * accA.z + s3 * accA.w;
  __syncthreads();
  if (tid == 0)
    atomicAdd(out, (wsum[0] + wsum[1]) + (wsum[2] + wsum[3]));
}

extern "C" void kernel_launch(void* const* d_in, const int* in_sizes, int n_in,
                              void* d_out, int out_size, void* d_ws, size_t ws_size,
                              hipStream_t stream) {
  const float* hidden = (const float*)d_in[0];  // [1,1,T,H] fp32
  const float* W      = (const float*)d_in[1];  // [1,E,H,2*INTER] fp32
  const float* mask   = (const float*)d_in[2];  // [1,E,T,1] fp32
  float* out = (float*)d_out;

  hipMemsetAsync(d_out, 0, sizeof(float), stream);   // graph-capturable memset node
  moe_dot<<<NBLK, 256, 0, stream>>>(hidden, W, mask, out);
}

// Round 7
// 393.754 us; speedup vs baseline: 1.0653x; 1.0653x over previous
//
#include <hip/hip_runtime.h>

// Problem constants
#define H_DIM 2048
#define E_DIM 8
#define T_DIM 2048
#define F_DIM 4096                 // INTER*2
#define NBLK  2048                 // 8 e * 256 h-chunks; exactly 8 blocks/CU
#define HCHUNK 8                   // h-columns per block

typedef float f32x4 __attribute__((ext_vector_type(4)));

// result = sum_{e,h} A[e,h]*B[e,h];  A = sum_t mask[e,t]*hidden[t,h];  B = sum_f W[e,h,f]
// R7: R5's proven producer-wave structure, re-parameterized for 2x occupancy.
// R6's per-wave A-gather (64 lines/instr, 16B used each) regressed 3x -- reverted
// to the producer layout (full 64B lines per A instruction). Change vs R5:
// HCHUNK 16->8, NBLK 1024->2048, 2 W-rows/wave, launch_bounds(256,8) -> 64-VGPR
// cap -> 8 blocks/CU = 32 waves/CU. Doubles in-flight HBM bytes to lift the
// stream from its latency-bound 5.2 TB/s toward the ~6.4 TB/s ceiling.
__global__ __launch_bounds__(256, 8) void moe_dot(
    const float* __restrict__ hidden,   // [T, H]
    const float* __restrict__ W,        // [E, H, F]
    const float* __restrict__ mask,     // [E, T]
    float* __restrict__ out) {
  const int tid  = threadIdx.x;
  const int bid  = blockIdx.x;
  const int e    = bid >> 8;                // 0..7
  const int h0   = (bid & 255) * HCHUNK;    // 0..2040
  const int wave = tid >> 6;
  const int lane = tid & 63;

  __shared__ float m_lds[T_DIM];            // 8 KB: mask row (producer-only)
  __shared__ float A_val[HCHUNK];           // A[e, h0+i]
  __shared__ float wsum[4];

  const size_t wbase = ((size_t)e * H_DIM + h0) * F_DIM;
  const int awave = bid & 3;                // rotate producer across SIMDs

  if (wave == awave) {
    // ---- producer: stage mask[e,:] (8 KB, wave-private, no barrier) ----
    const f32x4* m4 = (const f32x4*)(mask + (size_t)e * T_DIM);
    f32x4* l4 = (f32x4*)m_lds;
    #pragma unroll
    for (int i = 0; i < 8; ++i) l4[lane + (i << 6)] = m4[lane + (i << 6)];

    // ---- A[h0+hh] = sum_t mask[t]*hidden[t,hh]: lane=(ttg,hq), 64 iters ----
    // wave reads 32 rows x 32B per instr; h-sibling block consumes other half.
    const int hq  = lane & 1;
    const int ttg = lane >> 1;              // 0..31
    const float* hp = hidden + h0 + (hq << 2);
    f32x4 accA = (f32x4)0.f;
    #pragma unroll 8
    for (int k = 0; k < 64; ++k) {
      int t = ttg + (k << 5);
      accA += *(const f32x4*)(hp + (size_t)t * H_DIM) * m_lds[t];   // 2-way bcast, conflict-free
    }
    #pragma unroll
    for (int off = 2; off <= 32; off <<= 1) {
      accA.x += __shfl_down(accA.x, off, 64);
      accA.y += __shfl_down(accA.y, off, 64);
      accA.z += __shfl_down(accA.z, off, 64);
      accA.w += __shfl_down(accA.w, off, 64);
    }
    if (lane < 2) ((f32x4*)A_val)[lane] = accA;   // lanes 0-1 hold the 2 h-quads
  }

  // ---- all 4 waves stream 2 contiguous W rows each (32 KB/wave) ----
  const int r0 = wave << 1;
  const f32x4* rp = (const f32x4*)(W + wbase + (size_t)r0 * F_DIM);
  f32x4 a0 = (f32x4)0.f, a1 = (f32x4)0.f;
  #pragma unroll 4
  for (int i = 0; i < 16; ++i) {
    int idx = lane + (i << 6);
    a0 += rp[idx];
    a1 += rp[idx + 1024];                   // +1 row (4096 floats)
  }
  float s0 = (a0.x + a0.y) + (a0.z + a0.w);
  float s1 = (a1.x + a1.y) + (a1.z + a1.w);
  #pragma unroll
  for (int off = 32; off > 0; off >>= 1) {  // 2 ILP'd shuffle chains
    s0 += __shfl_down(s0, off, 64);
    s1 += __shfl_down(s1, off, 64);
  }

  __syncthreads();                          // A_val visible to all waves
  if (lane == 0)
    wsum[wave] = s0 * A_val[r0] + s1 * A_val[r0 + 1];
  __syncthreads();
  if (tid == 0)
    atomicAdd(out, (wsum[0] + wsum[1]) + (wsum[2] + wsum[3]));
}

extern "C" void kernel_launch(void* const* d_in, const int* in_sizes, int n_in,
                              void* d_out, int out_size, void* d_ws, size_t ws_size,
                              hipStream_t stream) {
  const float* hidden = (const float*)d_in[0];  // [1,1,T,H] fp32
  const float* W      = (const float*)d_in[1];  // [1,E,H,2*INTER] fp32
  const float* mask   = (const float*)d_in[2];  // [1,E,T,1] fp32
  float* out = (float*)d_out;

  hipMemsetAsync(d_out, 0, sizeof(float), stream);   // graph-capturable memset node
  moe_dot<<<NBLK, 256, 0, stream>>>(hidden, W, mask, out);
}

// Round 8
// 379.237 us; speedup vs baseline: 1.1061x; 1.0383x over previous
//
#include <hip/hip_runtime.h>

// Problem constants
#define H_DIM 2048
#define E_DIM 8
#define T_DIM 2048
#define F_DIM 4096                 // INTER*2
#define NBLK  1024                 // 8 e * 128 h-chunks; exactly 4 blocks/CU, uniform
#define HCHUNK 16                  // h-columns per block

typedef float f32x4 __attribute__((ext_vector_type(4)));

// result = sum_{e,h} A[e,h]*B[e,h];  A = sum_t mask[e,t]*hidden[t,h];  B = sum_f W[e,h,f]
// R8 = REVERT TO R5 (session best, 378.5us). Ledger of failed alternatives:
//   R6 per-wave A-gather: 419 (16B-of-64B line sectoring on hidden, 4x amp)
//   R7 2x-occupancy HCHUNK=8: 394 (halved per-wave MLP cancels wave doubling;
//      half-line hidden reads + doubled mask staging add traffic)
// R5 structure: balanced wave specialization. All 4 waves stream 4 W-rows
// (64KB contiguous each, unroll 4 -> 16 outstanding 1KB wave-loads); the
// producer wave (rotates with bid&3) first computes the block's 16 A values
// from full-64B-line hidden reads (L2-shared across the 8 e-sibling blocks on
// the same XCD), lagging ~2us as a tail. Single barrier pair in the epilogue.
__global__ __launch_bounds__(256, 4) void moe_dot(
    const float* __restrict__ hidden,   // [T, H]
    const float* __restrict__ W,        // [E, H, F]
    const float* __restrict__ mask,     // [E, T]
    float* __restrict__ out) {
  const int tid  = threadIdx.x;
  const int bid  = blockIdx.x;
  const int e    = bid >> 7;                // 0..7
  const int h0   = (bid & 127) * HCHUNK;    // 0..2032
  const int wave = tid >> 6;
  const int lane = tid & 63;

  __shared__ float m_lds[T_DIM];            // 8 KB: mask row (producer-only)
  __shared__ float A_val[HCHUNK];           // A[e, h0+i]
  __shared__ float wsum[4];

  const size_t wbase = ((size_t)e * H_DIM + h0) * F_DIM;
  const int awave = bid & 3;                // rotate producer across SIMDs

  if (wave == awave) {
    // ---- producer: stage mask[e,:] (8 KB, wave-private, no barrier) ----
    const f32x4* m4 = (const f32x4*)(mask + (size_t)e * T_DIM);
    f32x4* l4 = (f32x4*)m_lds;
    #pragma unroll
    for (int i = 0; i < 8; ++i) l4[lane + (i << 6)] = m4[lane + (i << 6)];

    // ---- A[h0+hh] = sum_t mask[t]*hidden[t,hh]: lane=(ttg,hq), 128 iters ----
    const int hq  = lane & 3;
    const int ttg = lane >> 2;              // 0..15
    const float* hp = hidden + h0 + (hq << 2);
    f32x4 accA = (f32x4)0.f;
    #pragma unroll 8
    for (int k = 0; k < 128; ++k) {
      int t = ttg + (k << 4);
      accA += *(const f32x4*)(hp + (size_t)t * H_DIM) * m_lds[t];
    }
    #pragma unroll
    for (int off = 4; off <= 32; off <<= 1) {
      accA.x += __shfl_down(accA.x, off, 64);
      accA.y += __shfl_down(accA.y, off, 64);
      accA.z += __shfl_down(accA.z, off, 64);
      accA.w += __shfl_down(accA.w, off, 64);
    }
    if (lane < 4) ((f32x4*)A_val)[lane] = accA;   // lanes 0-3 hold h-quads 0-3
  }

  // ---- all 4 waves stream 4 contiguous W rows each (64 KB/wave) ----
  const int r0 = wave << 2;
  const f32x4* rp = (const f32x4*)(W + wbase + (size_t)r0 * F_DIM);
  f32x4 a0 = (f32x4)0.f, a1 = (f32x4)0.f, a2 = (f32x4)0.f, a3 = (f32x4)0.f;
  #pragma unroll 4
  for (int i = 0; i < 16; ++i) {
    int idx = lane + (i << 6);
    a0 += rp[idx];
    a1 += rp[idx + 1024];                   // +1 row (4096 floats)
    a2 += rp[idx + 2048];
    a3 += rp[idx + 3072];
  }
  float s0 = (a0.x + a0.y) + (a0.z + a0.w);
  float s1 = (a1.x + a1.y) + (a1.z + a1.w);
  float s2 = (a2.x + a2.y) + (a2.z + a2.w);
  float s3 = (a3.x + a3.y) + (a3.z + a3.w);
  #pragma unroll
  for (int off = 32; off > 0; off >>= 1) {  // 4 ILP'd shuffle chains
    s0 += __shfl_down(s0, off, 64);
    s1 += __shfl_down(s1, off, 64);
    s2 += __shfl_down(s2, off, 64);
    s3 += __shfl_down(s3, off, 64);
  }

  __syncthreads();                          // A_val visible to all waves
  if (lane == 0)
    wsum[wave] = s0 * A_val[r0]     + s1 * A_val[r0 + 1]
               + s2 * A_val[r0 + 2] + s3 * A_val[r0 + 3];
  __syncthreads();
  if (tid == 0)
    atomicAdd(out, (wsum[0] + wsum[1]) + (wsum[2] + wsum[3]));
}

extern "C" void kernel_launch(void* const* d_in, const int* in_sizes, int n_in,
                              void* d_out, int out_size, void* d_ws, size_t ws_size,
                              hipStream_t stream) {
  const float* hidden = (const float*)d_in[0];  // [1,1,T,H] fp32
  const float* W      = (const float*)d_in[1];  // [1,E,H,2*INTER] fp32
  const float* mask   = (const float*)d_in[2];  // [1,E,T,1] fp32
  float* out = (float*)d_out;

  hipMemsetAsync(d_out, 0, sizeof(float), stream);   // graph-capturable memset node
  moe_dot<<<NBLK, 256, 0, stream>>>(hidden, W, mask, out);
}